// Round 1
// baseline (160.845 us; speedup 1.0000x reference)
//
#include <hip/hip_runtime.h>

// ConvSBS fused: stage1 (per-pixel core contraction) + stage2 (ring bond
// contraction) in one kernel. Crop removes all padded regions -> pure 2x2
// stencil:
//   out[b,y,x,pqrs] = sum_{ijkl} M0p[i,j] M1q[j,k] M2r[k,l] M3s[l,i]
//   M0 = t0(y,x), M1 = t1(y,x+1), M2 = t2(y+1,x), M3 = t3(y+1,x+1)
//   t_c[q,l,r] = sum_{a,b} cores[c,q,l,r,a,b] * ch0[pix,a] * ch1[pix,b]

#define NB 8
#define NH 128
#define NW 128
#define HO 127
#define WO 127
#define CH1_OFF (NB*NH*NW*4)   // 524288 floats

// 6-step DPP wave64 sum; full sum lands in lane 63. All on the VALU pipe.
#define DPP_ADD(v, ctrl) \
  ((v) + __int_as_float(__builtin_amdgcn_update_dpp( \
      0, __float_as_int(v), (ctrl), 0xf, 0xf, true)))

__device__ __forceinline__ float wave_sum64(float v) {
  v = DPP_ADD(v, 0x111);  // row_shr:1
  v = DPP_ADD(v, 0x112);  // row_shr:2
  v = DPP_ADD(v, 0x114);  // row_shr:4
  v = DPP_ADD(v, 0x118);  // row_shr:8  -> lane 15 of each row16 has row sum
  v = DPP_ADD(v, 0x142);  // row_bcast:15
  v = DPP_ADD(v, 0x143);  // row_bcast:31 -> lane 63 has full sum
  return v;
}

__device__ __forceinline__ void ldrow(const float* p, float* dst) {
  float4 r0 = *(const float4*)p;
  float4 r1 = *(const float4*)(p + 4);
  dst[0] = r0.x; dst[1] = r0.y; dst[2] = r0.z; dst[3] = r0.w;
  dst[4] = r1.x; dst[5] = r1.y; dst[6] = r1.z; dst[7] = r1.w;
}

__device__ __forceinline__ float dot8(const float* a, const float* b) {
  float s = 0.f;
#pragma unroll
  for (int j = 0; j < 8; ++j) s = fmaf(a[j], b[j], s);
  return s;
}

// matrix stride 68 floats: decorrelates banks, keeps 16B alignment (272B)
#define MSTRIDE 68

__global__ __launch_bounds__(256, 2)
void convsbs_fused(const float* __restrict__ ch,
                   const float* __restrict__ cores,
                   float* __restrict__ out) {
  const int tid  = threadIdx.x;
  const int lane = tid & 63;
  const int wid  = tid >> 6;
  const int m8 = lane >> 3;    // matrix id 0..7  (core c = m8>>1, q = m8&1)
  const int x8 = lane & 7;     // row index (cores 0,2) / col index (cores 1,3)
  const int c  = m8 >> 1;
  const int q  = m8 & 1;

  __shared__ __align__(16) float mlds[4][8 * MSTRIDE];
  float* mybuf = mlds[wid];

  // ---- per-lane weights in registers: 8 chunks of 16 floats.
  // cores layout: [c][q][l][r][a][b], (a,b) contiguous (16 floats).
  // cores 0,2: chunk j = W[c][q][x8][j][:]  (row x8 of the bond matrix)
  // cores 1,3: chunk j = W[c][q][j][x8][:]  (col x8 -> stored as T row)
  float w[8][16];
  {
    const float* wb = cores + (c * 2 + q) * 1024;  // 64 (l,r) * 16
#pragma unroll
    for (int j = 0; j < 8; ++j) {
      const int lr = (c & 1) ? (j * 8 + x8) : (x8 * 8 + j);
      const float4* p4 = (const float4*)(wb + lr * 16);
#pragma unroll
      for (int t = 0; t < 4; ++t) {
        float4 f = p4[t];
        w[j][t * 4 + 0] = f.x; w[j][t * 4 + 1] = f.y;
        w[j][t * 4 + 2] = f.z; w[j][t * 4 + 3] = f.w;
      }
    }
  }

  const int drow = c >> 1;   // stencil row offset for this lane's core
  const int dcol = c & 1;    // stencil col offset

  // persistent blocks: 4064 slots = (8 b * 127 y) * 4; wave -> x-window
  for (int slot = blockIdx.x; slot < 4064; slot += gridDim.x) {
    const int g  = slot >> 2;
    const int xw = ((slot & 3) << 2) | wid;  // 0..15, window of 8 x's
    const int b  = g / 127;
    const int y  = g - b * 127;

#pragma unroll 1
    for (int px = 0; px < 8; ++px) {
      int x = xw * 8 + px;
      const bool valid = (x < WO);
      if (!valid) x = WO - 1;  // keep loop uniform for barriers

      // ---------------- stage 1 ----------------
      const int row = y + drow;
      const int col = x + dcol;
      const float* cp = ch + ((b * NH + row) * NW + col) * 4;
      const float4 v0 = *(const float4*)cp;              // ch0[a]
      const float4 v1 = *(const float4*)(cp + CH1_OFF);  // ch1[b]
      float pa[4] = {v0.x, v0.y, v0.z, v0.w};
      float pb[4] = {v1.x, v1.y, v1.z, v1.w};
      float P[16];
#pragma unroll
      for (int a = 0; a < 4; ++a)
#pragma unroll
        for (int bb = 0; bb < 4; ++bb) P[a * 4 + bb] = pa[a] * pb[bb];

      float acc[8];
#pragma unroll
      for (int j = 0; j < 8; ++j) {
        float s = 0.f;
#pragma unroll
        for (int ab = 0; ab < 16; ++ab) s = fmaf(w[j][ab], P[ab], s);
        acc[j] = s;
      }
      // write my row (cores 1,3 rows are already transposed)
      float* wp = mybuf + m8 * MSTRIDE + x8 * 8;
      *(float4*)(wp)     = make_float4(acc[0], acc[1], acc[2], acc[3]);
      *(float4*)(wp + 4) = make_float4(acc[4], acc[5], acc[6], acc[7]);

      __syncthreads();  // stage1 writes -> stage2 reads (cross-lane)

      // ---------------- stage 2 ----------------
      const int i = m8;  // lane = (i,k)
      const int k = x8;
      float A0[8], A1[8], B0[8], B1[8];
      // C_pq[i,k] = dot( row_i(M0p), row_k(M1qT) )
      ldrow(mybuf + 0 * MSTRIDE + i * 8, A0);
      ldrow(mybuf + 1 * MSTRIDE + i * 8, A1);
      ldrow(mybuf + 2 * MSTRIDE + k * 8, B0);
      ldrow(mybuf + 3 * MSTRIDE + k * 8, B1);
      float Cv[4];
      Cv[0] = dot8(A0, B0); Cv[1] = dot8(A0, B1);
      Cv[2] = dot8(A1, B0); Cv[3] = dot8(A1, B1);
      // Dt_rs[i,k] = D_rs[k,i] = dot( row_k(M2r), row_i(M3sT) )
      ldrow(mybuf + 4 * MSTRIDE + k * 8, A0);
      ldrow(mybuf + 5 * MSTRIDE + k * 8, A1);
      ldrow(mybuf + 6 * MSTRIDE + i * 8, B0);
      ldrow(mybuf + 7 * MSTRIDE + i * 8, B1);
      float Dv[4];
      Dv[0] = dot8(A0, B0); Dv[1] = dot8(A0, B1);
      Dv[2] = dot8(A1, B0); Dv[3] = dot8(A1, B1);

      // out[pqrs] = sum_lanes Cv[pq] * Dv[rs];  o = (pq)*4 + (rs)
      float part[16];
#pragma unroll
      for (int pq = 0; pq < 4; ++pq)
#pragma unroll
        for (int rs = 0; rs < 4; ++rs) part[pq * 4 + rs] = Cv[pq] * Dv[rs];

#pragma unroll
      for (int o = 0; o < 16; ++o) part[o] = wave_sum64(part[o]);

      if (lane == 63 && valid) {
        float* ob = out + ((b * HO + y) * WO + x) * 16;
        *(float4*)(ob)      = make_float4(part[0],  part[1],  part[2],  part[3]);
        *(float4*)(ob + 4)  = make_float4(part[4],  part[5],  part[6],  part[7]);
        *(float4*)(ob + 8)  = make_float4(part[8],  part[9],  part[10], part[11]);
        *(float4*)(ob + 12) = make_float4(part[12], part[13], part[14], part[15]);
      }

      __syncthreads();  // stage2 reads -> next pixel's stage1 writes (WAR)
    }
  }
}

extern "C" void kernel_launch(void* const* d_in, const int* in_sizes, int n_in,
                              void* d_out, int out_size, void* d_ws, size_t ws_size,
                              hipStream_t stream) {
  (void)in_sizes; (void)n_in; (void)d_ws; (void)ws_size; (void)out_size;
  const float* ch    = (const float*)d_in[0];  // [2,8,128,128,4] f32
  const float* cores = (const float*)d_in[1];  // [4,2,8,8,4,4]   f32
  float* out = (float*)d_out;                  // [8,127,127,16]  f32
  convsbs_fused<<<512, 256, 0, stream>>>(ch, cores, out);
}

// Round 2
// 145.619 us; speedup vs baseline: 1.1046x; 1.1046x over previous
//
#include <hip/hip_runtime.h>

// ConvSBS fused, R2: register-resident weights (no per-pixel L1 re-stream),
// wave-local LDS fences instead of __syncthreads, cheap 3-step DPP k-reduce
// + LDS transpose + coalesced 16-lane store.
//
//   out[b,y,x,pqrs] = sum_{ik} C_pq[i,k] * D_rs[k,i]
//   C_pq = M0p(y,x) * M1q(y,x+1),  D_rs = M2r(y+1,x) * M3s(y+1,x+1)
//   t_c[q,l,r] = sum_{a,b} cores[c,q,l,r,a,b] * ch0[pos,a] * ch1[pos,b]

#define NB 8
#define NH 128
#define NW 128
#define HO 127
#define WO 127
#define CH1_OFF (NB*NH*NW*4)   // 524288 floats

// fused-DPP add (GCNDPPCombine folds mov_dpp+add -> v_add_f32_dpp)
#define DPP_ADD(v, ctrl) \
  ((v) + __int_as_float(__builtin_amdgcn_update_dpp( \
      0, __float_as_int(v), (ctrl), 0xf, 0xf, true)))

// wave-local LDS ordering: drain DS queue + stop compiler reordering.
// Each wave uses only its own LDS buffer, so no __syncthreads needed.
#define WAVE_LDS_FENCE() asm volatile("s_waitcnt lgkmcnt(0)" ::: "memory")

__device__ __forceinline__ void ldrow(const float* p, float* dst) {
  float4 r0 = *(const float4*)p;
  float4 r1 = *(const float4*)(p + 4);
  dst[0] = r0.x; dst[1] = r0.y; dst[2] = r0.z; dst[3] = r0.w;
  dst[4] = r1.x; dst[5] = r1.y; dst[6] = r1.z; dst[7] = r1.w;
}

__device__ __forceinline__ float dot8(const float* a, const float* b) {
  float s = 0.f;
#pragma unroll
  for (int j = 0; j < 8; ++j) s = fmaf(a[j], b[j], s);
  return s;
}

#define MSTRIDE 68   // matrix row-block stride (floats): bank-decorrelated, 16B-aligned
#define SSTRIDE 20   // S-transpose row stride (floats): 80B = 16B-aligned, banks spread

__global__ __launch_bounds__(256, 2)
void convsbs_fused(const float* __restrict__ ch,
                   const float* cores,          // NO restrict: keep w loads non-rematable
                   float* __restrict__ out) {
  const int tid  = threadIdx.x;
  const int lane = tid & 63;
  const int wid  = tid >> 6;
  const int m8 = lane >> 3;    // matrix id 0..7  (core c = m8>>1, q = m8&1)
  const int x8 = lane & 7;     // row (cores 0,2) / col (cores 1,3)
  const int c  = m8 >> 1;
  const int q  = m8 & 1;

  __shared__ __align__(16) float mlds[4][8 * MSTRIDE + 8 * SSTRIDE];
  float* mybuf = mlds[wid];
  float* sbuf  = mybuf + 8 * MSTRIDE;

  // ---- per-lane weights in registers: 8 chunks of 16 floats (128 VGPR).
  float w[8][16];
  {
    const float* wb = cores + (c * 2 + q) * 1024;
#pragma unroll
    for (int j = 0; j < 8; ++j) {
      const int lr = (c & 1) ? (j * 8 + x8) : (x8 * 8 + j);
      const float4* p4 = (const float4*)(wb + lr * 16);
#pragma unroll
      for (int t = 0; t < 4; ++t) {
        float4 f = p4[t];
        w[j][t * 4 + 0] = f.x; w[j][t * 4 + 1] = f.y;
        w[j][t * 4 + 2] = f.z; w[j][t * 4 + 3] = f.w;
      }
    }
  }
  // opaque barrier: weight loads may not be sunk/rematerialized into the loop
  asm volatile("" ::: "memory");

  const int drow = c >> 1;
  const int dcol = c & 1;

  // hoisted lane-constant LDS addresses
  float* wp  = mybuf + m8 * MSTRIDE + x8 * 8;          // stage1 write row
  const float* rA0 = mybuf + 0 * MSTRIDE + m8 * 8;     // stage2: i = m8, k = x8
  const float* rA1 = mybuf + 1 * MSTRIDE + m8 * 8;
  const float* rB0 = mybuf + 2 * MSTRIDE + x8 * 8;
  const float* rB1 = mybuf + 3 * MSTRIDE + x8 * 8;
  const float* rC0 = mybuf + 4 * MSTRIDE + x8 * 8;
  const float* rC1 = mybuf + 5 * MSTRIDE + x8 * 8;
  const float* rD0 = mybuf + 6 * MSTRIDE + m8 * 8;
  const float* rD1 = mybuf + 7 * MSTRIDE + m8 * 8;
  float* srow = sbuf + m8 * SSTRIDE;                   // k==7 lanes write row i=m8
  const int o16 = lane & 15;                           // output index for final sum

  for (int slot = blockIdx.x; slot < 4064; slot += gridDim.x) {
    const int g  = slot >> 2;
    const int xw = ((slot & 3) << 2) | wid;  // 0..15, window of 8 x's
    const int b  = g / 127;
    const int y  = g - b * 127;

#pragma unroll 1
    for (int px = 0; px < 8; ++px) {
      int x = xw * 8 + px;
      const bool valid = (x < WO);
      if (!valid) x = WO - 1;  // clamp: keep loads in-bounds, loop uniform

      // ---------------- stage 1 ----------------
      const int row = y + drow;
      const int col = x + dcol;
      const float* cp = ch + ((b * NH + row) * NW + col) * 4;
      const float4 v0 = *(const float4*)cp;
      const float4 v1 = *(const float4*)(cp + CH1_OFF);
      float pa[4] = {v0.x, v0.y, v0.z, v0.w};
      float pb[4] = {v1.x, v1.y, v1.z, v1.w};
      float P[16];
#pragma unroll
      for (int a = 0; a < 4; ++a)
#pragma unroll
        for (int bb = 0; bb < 4; ++bb) P[a * 4 + bb] = pa[a] * pb[bb];

      float acc[8];
#pragma unroll
      for (int j = 0; j < 8; ++j) {
        float s = 0.f;
#pragma unroll
        for (int ab = 0; ab < 16; ++ab) s = fmaf(w[j][ab], P[ab], s);
        acc[j] = s;
      }
      *(float4*)(wp)     = make_float4(acc[0], acc[1], acc[2], acc[3]);
      *(float4*)(wp + 4) = make_float4(acc[4], acc[5], acc[6], acc[7]);

      WAVE_LDS_FENCE();   // stage1 writes -> stage2 reads (same wave only)

      // ---------------- stage 2 ----------------
      float A0[8], A1[8], B0[8], B1[8];
      ldrow(rA0, A0); ldrow(rA1, A1); ldrow(rB0, B0); ldrow(rB1, B1);
      float Cv[4];
      Cv[0] = dot8(A0, B0); Cv[1] = dot8(A0, B1);
      Cv[2] = dot8(A1, B0); Cv[3] = dot8(A1, B1);
      ldrow(rC0, A0); ldrow(rC1, A1); ldrow(rD0, B0); ldrow(rD1, B1);
      float Dv[4];
      Dv[0] = dot8(A0, B0); Dv[1] = dot8(A0, B1);
      Dv[2] = dot8(A1, B0); Dv[3] = dot8(A1, B1);

      // per-lane products; reduce over k (= lane&7) with 3 fused DPP adds
      float part[16];
#pragma unroll
      for (int pq = 0; pq < 4; ++pq)
#pragma unroll
        for (int rs = 0; rs < 4; ++rs) {
          float p = Cv[pq] * Dv[rs];
          p = DPP_ADD(p, 0x111);  // row_shr:1
          p = DPP_ADD(p, 0x112);  // row_shr:2
          p = DPP_ADD(p, 0x114);  // row_shr:4 -> lanes k==7 hold sum over k
          part[pq * 4 + rs] = p;
        }

      // transpose through LDS: k==7 lanes (one per i) write 16 partials
      if ((lane & 7) == 7) {
        *(float4*)(srow)      = make_float4(part[0],  part[1],  part[2],  part[3]);
        *(float4*)(srow + 4)  = make_float4(part[4],  part[5],  part[6],  part[7]);
        *(float4*)(srow + 8)  = make_float4(part[8],  part[9],  part[10], part[11]);
        *(float4*)(srow + 12) = make_float4(part[12], part[13], part[14], part[15]);
      }

      WAVE_LDS_FENCE();   // transpose writes -> final-sum reads

      // final sum over i: 16 lanes each own one output element
      float ssum = 0.f;
#pragma unroll
      for (int i = 0; i < 8; ++i) ssum += sbuf[i * SSTRIDE + o16];

      if (valid && lane < 16)
        out[((b * HO + y) * WO + x) * 16 + o16] = ssum;

      WAVE_LDS_FENCE();   // WAR: reads done before next pixel's writes
    }
  }
}

extern "C" void kernel_launch(void* const* d_in, const int* in_sizes, int n_in,
                              void* d_out, int out_size, void* d_ws, size_t ws_size,
                              hipStream_t stream) {
  (void)in_sizes; (void)n_in; (void)d_ws; (void)ws_size; (void)out_size;
  const float* ch    = (const float*)d_in[0];  // [2,8,128,128,4] f32
  const float* cores = (const float*)d_in[1];  // [4,2,8,8,4,4]   f32
  float* out = (float*)d_out;                  // [8,127,127,16]  f32
  convsbs_fused<<<512, 256, 0, stream>>>(ch, cores, out);
}

// Round 3
// 141.494 us; speedup vs baseline: 1.1368x; 1.0292x over previous
//
#include <hip/hip_runtime.h>

// ConvSBS fused, R3: software-pipelined stage1/stage2 (double-buffered LDS,
// no runtime fences - wave-local DS ops execute in order), packed-fp32
// (v_pk_fma_f32) math, full 64-lane DPP reduction (no LDS transpose).
//
//   out[b,y,x,pqrs] = sum_{ik} C_pq[i,k] * D_rs[k,i]
//   C_pq = M0p(y,x) * M1q(y,x+1),  D_rs = M2r(y+1,x) * M3s(y+1,x+1)
//   t_c[q,l,r] = sum_{a,b} cores[c,q,l,r,a,b] * ch0[pos,a] * ch1[pos,b]

typedef float v2f __attribute__((ext_vector_type(2)));

#define NB 8
#define NH 128
#define NW 128
#define HO 127
#define WO 127
#define CH1_OFF (NB*NH*NW*4)   // 524288 floats
#define MSTRIDE 68             // per-matrix stride (floats), 16B-aligned

// compiler-only barrier: pins program order of LDS ops, costs 0 cycles.
// HW executes a wave's DS ops in order, so no s_waitcnt drain is needed for
// cross-lane same-wave LDS communication.
#define PIN() asm volatile("" ::: "memory")

#define DPP_ADD(v, ctrl) \
  ((v) + __int_as_float(__builtin_amdgcn_update_dpp( \
      0, __float_as_int(v), (ctrl), 0xf, 0xf, true)))

// full 64-lane sum via DPP prefix: result valid in lane 63
__device__ __forceinline__ float wred64(float v) {
  v = DPP_ADD(v, 0x111);  // row_shr:1
  v = DPP_ADD(v, 0x112);  // row_shr:2
  v = DPP_ADD(v, 0x114);  // row_shr:4
  v = DPP_ADD(v, 0x118);  // row_shr:8  -> lane15 of each row16 = row sum
  v = DPP_ADD(v, 0x142);  // row_bcast:15
  v = DPP_ADD(v, 0x143);  // row_bcast:31 -> lane 63 = total
  return v;
}

__device__ __forceinline__ v2f pkfma(v2f a, v2f b, v2f c) {
#if __has_builtin(__builtin_elementwise_fma)
  return __builtin_elementwise_fma(a, b, c);
#else
  v2f r; r.x = fmaf(a.x, b.x, c.x); r.y = fmaf(a.y, b.y, c.y); return r;
#endif
}

__device__ __forceinline__ void ldrow2(const float* p, v2f* d) {
  float4 r0 = *(const float4*)p;
  float4 r1 = *(const float4*)(p + 4);
  d[0] = (v2f){r0.x, r0.y}; d[1] = (v2f){r0.z, r0.w};
  d[2] = (v2f){r1.x, r1.y}; d[3] = (v2f){r1.z, r1.w};
}

__device__ __forceinline__ float dot8v(const v2f* a, const v2f* b) {
  v2f s = a[0] * b[0];
  s = pkfma(a[1], b[1], s);
  s = pkfma(a[2], b[2], s);
  s = pkfma(a[3], b[3], s);
  return s.x + s.y;
}

__global__ __launch_bounds__(256, 2)
void convsbs_fused(const float* __restrict__ ch,
                   const float* cores,          // no restrict: loads not rematable
                   float* __restrict__ out) {
  const int tid  = threadIdx.x;
  const int lane = tid & 63;
  const int wid  = tid >> 6;
  const int m8 = lane >> 3;    // matrix id 0..7 (core c = m8>>1, q = m8&1)
  const int x8 = lane & 7;     // row (cores 0,2) / col (cores 1,3)
  const int c  = m8 >> 1;
  const int q  = m8 & 1;

  __shared__ __align__(16) float mlds[4][2][8 * MSTRIDE];
  float* buf0 = mlds[wid][0];
  float* buf1 = mlds[wid][1];

  // ---- per-lane weights: 8 chunks of 16 floats, packed as v2f[8][8]
  v2f w2[8][8];
  {
    const float* wb = cores + (c * 2 + q) * 1024;
#pragma unroll
    for (int j = 0; j < 8; ++j) {
      const int lr = (c & 1) ? (j * 8 + x8) : (x8 * 8 + j);
      const float4* p4 = (const float4*)(wb + lr * 16);
#pragma unroll
      for (int t = 0; t < 4; ++t) {
        float4 f = p4[t];
        w2[j][t * 2]     = (v2f){f.x, f.y};
        w2[j][t * 2 + 1] = (v2f){f.z, f.w};
      }
    }
  }
  PIN();

  const int drow = c >> 1;
  const int dcol = c & 1;
  const int wp_off = m8 * MSTRIDE + x8 * 8;   // stage1 write offset

  // stage1: acc[8] = W_row(j) . (ch0 x ch1)
  auto s1 = [&](const float4& u0, const float4& u1, float* acc) {
    v2f pb01 = {u1.x, u1.y}, pb23 = {u1.z, u1.w};
    float pa[4] = {u0.x, u0.y, u0.z, u0.w};
    v2f P[8];
#pragma unroll
    for (int a = 0; a < 4; ++a) {
      v2f s = {pa[a], pa[a]};
      P[2 * a]     = s * pb01;
      P[2 * a + 1] = s * pb23;
    }
#pragma unroll
    for (int j = 0; j < 8; ++j) {
      v2f s = w2[j][0] * P[0];
#pragma unroll
      for (int f = 1; f < 8; ++f) s = pkfma(w2[j][f], P[f], s);
      acc[j] = s.x + s.y;
    }
  };

  for (int slot = blockIdx.x; slot < 4064; slot += gridDim.x) {
    const int g  = slot >> 2;
    const int xw = ((slot & 3) << 2) | wid;  // 0..15
    const int b  = g / 127;
    const int y  = g - b * 127;
    const int xbase = xw * 8;
    const float* chbase = ch + ((b * NH + (y + drow)) * NW + dcol) * 4;
    float* obase = out + (size_t)((b * HO + y) * WO) * 16;

    float4 u0[2], u1[2];
    // prologue: load px 0,1; stage1(0) -> buf0
    {
      int xc = xbase;     if (xc > WO - 1) xc = WO - 1;
      const float* cp = chbase + xc * 4;
      u0[0] = *(const float4*)cp; u1[0] = *(const float4*)(cp + CH1_OFF);
      xc = xbase + 1;     if (xc > WO - 1) xc = WO - 1;
      cp = chbase + xc * 4;
      u0[1] = *(const float4*)cp; u1[1] = *(const float4*)(cp + CH1_OFF);
    }
    {
      float acc[8];
      s1(u0[0], u1[0], acc);
      float* wp = buf0 + wp_off;
      *(float4*)(wp)     = make_float4(acc[0], acc[1], acc[2], acc[3]);
      *(float4*)(wp + 4) = make_float4(acc[4], acc[5], acc[6], acc[7]);
    }
    PIN();

#pragma unroll
    for (int px = 0; px < 8; ++px) {
      float* cur = (px & 1) ? buf1 : buf0;
      float* nxt = (px & 1) ? buf0 : buf1;

      // 1. issue stage2 reads for px (written last iteration / prologue)
      v2f A0[4], A1[4], B0[4], B1[4], C0[4], C1[4], D0[4], D1[4];
      ldrow2(cur + 0 * MSTRIDE + m8 * 8, A0);   // M0p rows i
      ldrow2(cur + 1 * MSTRIDE + m8 * 8, A1);
      ldrow2(cur + 2 * MSTRIDE + x8 * 8, B0);   // M1qT rows k
      ldrow2(cur + 3 * MSTRIDE + x8 * 8, B1);
      ldrow2(cur + 4 * MSTRIDE + x8 * 8, C0);   // M2r rows k
      ldrow2(cur + 5 * MSTRIDE + x8 * 8, C1);
      ldrow2(cur + 6 * MSTRIDE + m8 * 8, D0);   // M3sT rows i
      ldrow2(cur + 7 * MSTRIDE + m8 * 8, D1);

      // 2. prefetch channel loads for px+2
      if (px + 2 < 8) {
        int xc = xbase + px + 2; if (xc > WO - 1) xc = WO - 1;
        const float* cp = chbase + xc * 4;
        u0[px & 1] = *(const float4*)cp;
        u1[px & 1] = *(const float4*)(cp + CH1_OFF);
      }

      // 3. stage1 for px+1 (VALU work hiding the ds_read latency), write nxt
      if (px + 1 < 8) {
        float acc[8];
        s1(u0[(px + 1) & 1], u1[(px + 1) & 1], acc);
        float* wp = nxt + wp_off;
        *(float4*)(wp)     = make_float4(acc[0], acc[1], acc[2], acc[3]);
        *(float4*)(wp + 4) = make_float4(acc[4], acc[5], acc[6], acc[7]);
      }
      PIN();

      // 4. stage2 finish for px
      float Cv[4], Dv[4];
      Cv[0] = dot8v(A0, B0); Cv[1] = dot8v(A0, B1);
      Cv[2] = dot8v(A1, B0); Cv[3] = dot8v(A1, B1);
      Dv[0] = dot8v(C0, D0); Dv[1] = dot8v(C0, D1);
      Dv[2] = dot8v(C1, D0); Dv[3] = dot8v(C1, D1);

      float r[16];
#pragma unroll
      for (int pq = 0; pq < 4; ++pq)
#pragma unroll
        for (int rs = 0; rs < 4; ++rs)
          r[pq * 4 + rs] = wred64(Cv[pq] * Dv[rs]);

      const int x = xbase + px;
      if (lane == 63 && x < WO) {
        float* ob = obase + x * 16;
        *(float4*)(ob)      = make_float4(r[0],  r[1],  r[2],  r[3]);
        *(float4*)(ob + 4)  = make_float4(r[4],  r[5],  r[6],  r[7]);
        *(float4*)(ob + 8)  = make_float4(r[8],  r[9],  r[10], r[11]);
        *(float4*)(ob + 12) = make_float4(r[12], r[13], r[14], r[15]);
      }
      PIN();
    }
  }
}

extern "C" void kernel_launch(void* const* d_in, const int* in_sizes, int n_in,
                              void* d_out, int out_size, void* d_ws, size_t ws_size,
                              hipStream_t stream) {
  (void)in_sizes; (void)n_in; (void)d_ws; (void)ws_size; (void)out_size;
  const float* ch    = (const float*)d_in[0];  // [2,8,128,128,4] f32
  const float* cores = (const float*)d_in[1];  // [4,2,8,8,4,4]   f32
  float* out = (float*)d_out;                  // [8,127,127,16]  f32
  convsbs_fused<<<512, 256, 0, stream>>>(ch, cores, out);
}

// Round 4
// 128.355 us; speedup vs baseline: 1.2531x; 1.1024x over previous
//
#include <hip/hip_runtime.h>

// ConvSBS fused, R4: f16 datapath. Weights packed half2 in 64 VGPRs (fits a
// 3-wave/SIMD budget -> no AGPR parking), v_dot2_f32_f16 for stage1+stage2
// (2 MACs/inst, f32 accum), f16 LDS t-buffer (1 ds op per row), 4-step DPP
// reduction + LDS gather + coalesced 16-lane store. Occupancy 2->3 waves/SIMD.
//
//   out[b,y,x,pqrs] = sum_{ik} C_pq[i,k] * D_rs[k,i]
//   C_pq = M0p(y,x)*M1q(y,x+1),  D_rs = M2r(y+1,x)*M3s(y+1,x+1)
//   t_c[q,l,r] = sum_{ab} cores[c,q,l,r,a,b]*ch0[pos,a]*ch1[pos,b]

typedef _Float16 half2 __attribute__((ext_vector_type(2)));
typedef _Float16 h8    __attribute__((ext_vector_type(8)));

#define NB 8
#define NH 128
#define NW 128
#define HO 127
#define WO 127
#define CH1_OFF (NB*NH*NW*4)   // 524288 floats
#define MSTR_H 80              // matrix stride in halfs (160B): writes 2-way (free)
#define SSTR  20               // sbuf row stride in floats

#define PIN() asm volatile("" ::: "memory")

#define DPP_ADD(v, ctrl) \
  ((v) + __int_as_float(__builtin_amdgcn_update_dpp( \
      0, __float_as_int(v), (ctrl), 0xf, 0xf, true)))

// sum over each 16-lane row; result valid in lanes 15 mod 16
__device__ __forceinline__ float rowsum16(float v) {
  v = DPP_ADD(v, 0x111);
  v = DPP_ADD(v, 0x112);
  v = DPP_ADD(v, 0x114);
  v = DPP_ADD(v, 0x118);
  return v;
}

#define FDOT2(a, b, c) __builtin_amdgcn_fdot2((a), (b), (c), false)

__device__ __forceinline__ float dot8h(const half2* a, const half2* b) {
  float s = FDOT2(a[0], b[0], 0.f);
  s = FDOT2(a[1], b[1], s);
  s = FDOT2(a[2], b[2], s);
  s = FDOT2(a[3], b[3], s);
  return s;
}

__device__ __forceinline__ void ldrowh(const _Float16* p, half2* d) {
  h8 v = *(const h8*)p;
  d[0] = (half2){v[0], v[1]};
  d[1] = (half2){v[2], v[3]};
  d[2] = (half2){v[4], v[5]};
  d[3] = (half2){v[6], v[7]};
}

__global__ __launch_bounds__(256, 3)
void convsbs_fused(const float* __restrict__ ch,
                   const float* cores,          // no restrict: keep loads pinned
                   float* __restrict__ out) {
  const int tid  = threadIdx.x;
  const int lane = tid & 63;
  const int wid  = tid >> 6;
  const int m8 = lane >> 3;    // matrix id 0..7 (core c = m8>>1, q = m8&1)
  const int x8 = lane & 7;     // row (cores 0,2) / col (cores 1,3)
  const int c  = m8 >> 1;
  const int q  = m8 & 1;

  __shared__ __align__(16) _Float16 tlds[4][2][8 * MSTR_H];
  __shared__ __align__(16) float    slds[4][4 * SSTR];
  _Float16* buf0 = tlds[wid][0];
  _Float16* buf1 = tlds[wid][1];
  float*    sbuf = slds[wid];

  // ---- per-lane weights: 8 chunks of 16, packed half2 -> 64 VGPRs
  half2 wh[8][8];
  {
    const float* wb = cores + (c * 2 + q) * 1024;
#pragma unroll
    for (int j = 0; j < 8; ++j) {
      const int lr = (c & 1) ? (j * 8 + x8) : (x8 * 8 + j);
      const float4* p4 = (const float4*)(wb + lr * 16);
#pragma unroll
      for (int t = 0; t < 4; ++t) {
        float4 f = p4[t];
        wh[j][2 * t]     = (half2){(_Float16)f.x, (_Float16)f.y};
        wh[j][2 * t + 1] = (half2){(_Float16)f.z, (_Float16)f.w};
      }
    }
  }
  PIN();

  const int drow = c >> 1;
  const int dcol = c & 1;
  const int wp_off = m8 * MSTR_H + x8 * 8;   // stage1 write offset (halfs)
  const int o16 = lane & 15;
  const int rrow = lane >> 4;                // 16-lane row id 0..3

  // stage1: row of 8 t-values from (ch0 x ch1) . W, packed to h8
  auto s1 = [&](const float4& u0, const float4& u1, _Float16* dst) {
    float pa[4] = {u0.x, u0.y, u0.z, u0.w};
    float pb[4] = {u1.x, u1.y, u1.z, u1.w};
    half2 P[8];
#pragma unroll
    for (int a = 0; a < 4; ++a) {
      P[2 * a]     = (half2){(_Float16)(pa[a] * pb[0]), (_Float16)(pa[a] * pb[1])};
      P[2 * a + 1] = (half2){(_Float16)(pa[a] * pb[2]), (_Float16)(pa[a] * pb[3])};
    }
    h8 r;
#pragma unroll
    for (int j = 0; j < 8; ++j) {
      float s = FDOT2(wh[j][0], P[0], 0.f);
#pragma unroll
      for (int f = 1; f < 8; ++f) s = FDOT2(wh[j][f], P[f], s);
      r[j] = (_Float16)s;
    }
    *(h8*)dst = r;
  };

  for (int slot = blockIdx.x; slot < 4064; slot += gridDim.x) {
    const int g  = slot >> 2;
    const int xw = ((slot & 3) << 2) | wid;  // 0..15
    const int b  = g / 127;
    const int y  = g - b * 127;
    const int xbase = xw * 8;
    const float* chbase = ch + ((b * NH + (y + drow)) * NW + dcol) * 4;
    float* obase = out + (size_t)((b * HO + y) * WO) * 16;

    float4 u0[2], u1[2];
    {
      int xc = xbase;     if (xc > WO - 1) xc = WO - 1;
      const float* cp = chbase + xc * 4;
      u0[0] = *(const float4*)cp; u1[0] = *(const float4*)(cp + CH1_OFF);
      xc = xbase + 1;     if (xc > WO - 1) xc = WO - 1;
      cp = chbase + xc * 4;
      u0[1] = *(const float4*)cp; u1[1] = *(const float4*)(cp + CH1_OFF);
    }
    s1(u0[0], u1[0], buf0 + wp_off);
    PIN();

#pragma unroll
    for (int px = 0; px < 8; ++px) {
      _Float16* cur = (px & 1) ? buf1 : buf0;
      _Float16* nxt = (px & 1) ? buf0 : buf1;

      // 1. stage2 reads for px
      half2 A0[4], A1[4], B0[4], B1[4], C0[4], C1[4], D0[4], D1[4];
      ldrowh(cur + 0 * MSTR_H + m8 * 8, A0);   // M0p row i
      ldrowh(cur + 1 * MSTR_H + m8 * 8, A1);
      ldrowh(cur + 2 * MSTR_H + x8 * 8, B0);   // M1qT row k
      ldrowh(cur + 3 * MSTR_H + x8 * 8, B1);
      ldrowh(cur + 4 * MSTR_H + x8 * 8, C0);   // M2r row k
      ldrowh(cur + 5 * MSTR_H + x8 * 8, C1);
      ldrowh(cur + 6 * MSTR_H + m8 * 8, D0);   // M3sT row i
      ldrowh(cur + 7 * MSTR_H + m8 * 8, D1);

      // 2. prefetch channels for px+2
      if (px + 2 < 8) {
        int xc = xbase + px + 2; if (xc > WO - 1) xc = WO - 1;
        const float* cp = chbase + xc * 4;
        u0[px & 1] = *(const float4*)cp;
        u1[px & 1] = *(const float4*)(cp + CH1_OFF);
      }

      // 3. stage1 for px+1 (hides ds_read latency)
      if (px + 1 < 8) s1(u0[(px + 1) & 1], u1[(px + 1) & 1], nxt + wp_off);
      PIN();

      // 4. stage2 finish
      float Cv[4], Dv[4];
      Cv[0] = dot8h(A0, B0); Cv[1] = dot8h(A0, B1);
      Cv[2] = dot8h(A1, B0); Cv[3] = dot8h(A1, B1);
      Dv[0] = dot8h(C0, D0); Dv[1] = dot8h(C0, D1);
      Dv[2] = dot8h(C1, D0); Dv[3] = dot8h(C1, D1);

      // reduce: 4-step DPP rowsum, lanes 15 mod 16 write float4 chunks
#pragma unroll
      for (int pq = 0; pq < 4; ++pq) {
        float4 rr;
        rr.x = rowsum16(Cv[pq] * Dv[0]);
        rr.y = rowsum16(Cv[pq] * Dv[1]);
        rr.z = rowsum16(Cv[pq] * Dv[2]);
        rr.w = rowsum16(Cv[pq] * Dv[3]);
        if ((lane & 15) == 15)
          *(float4*)(sbuf + rrow * SSTR + pq * 4) = rr;
      }
      PIN();

      // gather over the 4 row-groups; coalesced 16-lane store
      float v = sbuf[0 * SSTR + o16] + sbuf[1 * SSTR + o16]
              + sbuf[2 * SSTR + o16] + sbuf[3 * SSTR + o16];
      const int x = xbase + px;
      if (lane < 16 && x < WO) obase[x * 16 + o16] = v;
      PIN();
    }
  }
}

extern "C" void kernel_launch(void* const* d_in, const int* in_sizes, int n_in,
                              void* d_out, int out_size, void* d_ws, size_t ws_size,
                              hipStream_t stream) {
  (void)in_sizes; (void)n_in; (void)d_ws; (void)ws_size; (void)out_size;
  const float* ch    = (const float*)d_in[0];  // [2,8,128,128,4] f32
  const float* cores = (const float*)d_in[1];  // [4,2,8,8,4,4]   f32
  float* out = (float*)d_out;                  // [8,127,127,16]  f32
  convsbs_fused<<<768, 256, 0, stream>>>(ch, cores, out);
}

// Round 6
// 119.839 us; speedup vs baseline: 1.3422x; 1.0711x over previous
//
#include <hip/hip_runtime.h>

// ConvSBS fused, R5b: stage 1 on the matrix pipe (type-fixed rebuild of R5).
//   t[qlr, px] = W(512x16) . P(16ab x 8px)  via v_mfma_f32_16x16x16_f16,
// W resident as 32 A-fragments (64 VGPRs). Row-permuted W (cores 1,3 loaded
// in (q,r,l) order) makes the MFMA C-layout (row=quad*4+reg, col=lane&15)
// write contiguous 4-half runs in exactly the LDS layout stage 2 reads.
// Stage 2 (verified in R4) unchanged; reduction = R1-verified 6-step DPP.

typedef __fp16 h2 __attribute__((ext_vector_type(2)));
typedef __fp16 h4 __attribute__((ext_vector_type(4)));
typedef __fp16 h8 __attribute__((ext_vector_type(8)));
typedef float  f4 __attribute__((ext_vector_type(4)));

#define NB 8
#define NH 128
#define NW 128
#define HO 127
#define WO 127
#define CH1_OFF (NB*NH*NW*4)   // 524288 floats
#define PXSTR 648              // halfs per pixel slot: mult of 8 (b128 align), bank-spread
#define NSLOT 10               // 8 real px + dump region for the unused MFMA cols

#define DPP_ADD(v, ctrl) \
  ((v) + __int_as_float(__builtin_amdgcn_update_dpp( \
      0, __float_as_int(v), (ctrl), 0xf, 0xf, true)))

// full 64-lane sum; result valid in lane 63 (R1-verified)
__device__ __forceinline__ float wred64(float v) {
  v = DPP_ADD(v, 0x111);
  v = DPP_ADD(v, 0x112);
  v = DPP_ADD(v, 0x114);
  v = DPP_ADD(v, 0x118);
  v = DPP_ADD(v, 0x142);
  v = DPP_ADD(v, 0x143);
  return v;
}

#define FDOT2(a, b, c) __builtin_amdgcn_fdot2((a), (b), (c), false)
#define PKRTZ(a, b)    __builtin_amdgcn_cvt_pkrtz((a), (b))

__device__ __forceinline__ float dot8h(const h2* a, const h2* b) {
  float s = FDOT2(a[0], b[0], 0.f);
  s = FDOT2(a[1], b[1], s);
  s = FDOT2(a[2], b[2], s);
  s = FDOT2(a[3], b[3], s);
  return s;
}

__device__ __forceinline__ void ldrowh(const __fp16* p, h2* d) {
  h8 v = *(const h8*)p;
  d[0] = (h2){v[0], v[1]};
  d[1] = (h2){v[2], v[3]};
  d[2] = (h2){v[4], v[5]};
  d[3] = (h2){v[6], v[7]};
}

__global__ __launch_bounds__(256, 3)
void convsbs_fused(const float* __restrict__ ch,
                   const float* __restrict__ cores,
                   float* __restrict__ out) {
  const int tid  = threadIdx.x;
  const int lane = tid & 63;
  const int wid  = tid >> 6;
  const int quad = lane >> 4;   // MFMA k-group / C-row group
  const int nn   = lane & 15;   // MFMA m (A) / n (B,D) index
  const int m8   = lane >> 3;   // s2: i
  const int x8   = lane & 7;    // s2: k

  __shared__ __align__(16) __fp16 tlds[4][NSLOT * PXSTR];
  __fp16* tbuf = tlds[wid];
  // cols 8-15 of each MFMA are duplicates: their writes go to a dump region
  __fp16* wrbase = tbuf + (nn < 8 ? nn * PXSTR + quad * 4
                                  : 8 * PXSTR + (nn - 8) * 16 + quad * 4);

  // ---- W as 32 A-fragments: lane holds A[m=nn][k=quad*4+j], j=0..3.
  // cores layout [c][q][l][r][a*4+b]; k = quad*4+j -> a=quad, b=j (float4).
  // cores 0,2: rows ordered (q,l,r); cores 1,3: (q,r,l) -> transposed store,
  // matching stage 2's M1^T / M3^T row reads.
  h4 wf[4][8];
#pragma unroll
  for (int c = 0; c < 4; ++c)
#pragma unroll
    for (int bi = 0; bi < 8; ++bi) {
      const int rowIdx = bi * 16 + nn;       // 0..127 within core c
      const int q  = rowIdx >> 6;
      const int ua = (rowIdx >> 3) & 7;
      const int ub = rowIdx & 7;
      const int l = (c & 1) ? ub : ua;
      const int r = (c & 1) ? ua : ub;
      const float4 wv = *(const float4*)(
          cores + ((((c * 2 + q) * 8 + l) * 8 + r) << 4) + quad * 4);
      h2 p0 = PKRTZ(wv.x, wv.y), p1 = PKRTZ(wv.z, wv.w);
      wf[c][bi] = (h4){p0[0], p0[1], p1[0], p1[1]};
    }

  const int blk = blockIdx.x;       // one (b, y) row per block
  const int b = blk / 127;
  const int y = blk - b * 127;
  const int xq = wid * 32;          // wave's x-quarter: 4 tiles of 8
  const float* rowbase = ch + (size_t)((b * NH + y) * NW) * 4;
  float* obase = out + (size_t)((b * HO + y) * WO) * 16;

  float  a0[2][4];
  float4 a1[2][4];
  auto loadch = [&](int xtile, int bufi) {
#pragma unroll
    for (int c = 0; c < 4; ++c) {
      int col = xtile + x8 + (c & 1);
      col = col > 127 ? 127 : col;            // clamp (x=127 output is masked)
      const float* cp = rowbase + (((c >> 1) * NW) + col) * 4;
      a0[bufi][c] = cp[quad];                  // ch0[a=quad]
      a1[bufi][c] = *(const float4*)(cp + CH1_OFF);  // ch1[0..3]
    }
  };

  loadch(xq, 0);

#pragma unroll
  for (int t = 0; t < 4; ++t) {
    const int xtile = xq + t * 8;
    const int cb = t & 1;

    // B-fragments: B[k=ab][n=px] = ch0[a]*ch1[b] at core-shifted position
    h4 bf[4];
#pragma unroll
    for (int c = 0; c < 4; ++c) {
      const float s = a0[cb][c];
      const float4 v = a1[cb][c];
      h2 p0 = PKRTZ(s * v.x, s * v.y), p1 = PKRTZ(s * v.z, s * v.w);
      bf[c] = (h4){p0[0], p0[1], p1[0], p1[1]};
    }
    if (t < 3) loadch(xq + (t + 1) * 8, cb ^ 1);

    // ---- stage 1: 32 MFMAs; each C-frag -> one ds_write_b64.
    // addr(row'=bi*16+quad*4+reg) = c*160 + row' + (q?16:0); q=(row'>=64),
    // constant per bi. quad*4 and the pixel slot are folded into wrbase.
#pragma unroll
    for (int c = 0; c < 4; ++c)
#pragma unroll
      for (int bi = 0; bi < 8; ++bi) {
        f4 acc = __builtin_amdgcn_mfma_f32_16x16x16f16(
            wf[c][bi], bf[c], (f4){0.f, 0.f, 0.f, 0.f}, 0, 0, 0);
        h2 p0 = PKRTZ(acc[0], acc[1]), p1 = PKRTZ(acc[2], acc[3]);
        *(h4*)(wrbase + c * 160 + bi * 16 + (bi >= 4 ? 16 : 0)) =
            (h4){p0[0], p0[1], p1[0], p1[1]};
      }

    // ---- stage 2: unchanged from R4 (verified), R1-verified reduction
#pragma unroll 1
    for (int px = 0; px < 8; ++px) {
      const __fp16* pb = tbuf + px * PXSTR;
      h2 A0[4], A1[4], B0[4], B1[4], C0[4], C1[4], D0[4], D1[4];
      ldrowh(pb + 0 * 80 + m8 * 8, A0);   // M0_0 row i
      ldrowh(pb + 1 * 80 + m8 * 8, A1);   // M0_1 row i
      ldrowh(pb + 2 * 80 + x8 * 8, B0);   // M1_0^T row k
      ldrowh(pb + 3 * 80 + x8 * 8, B1);   // M1_1^T row k
      ldrowh(pb + 4 * 80 + x8 * 8, C0);   // M2_0 row k
      ldrowh(pb + 5 * 80 + x8 * 8, C1);   // M2_1 row k
      ldrowh(pb + 6 * 80 + m8 * 8, D0);   // M3_0^T row i
      ldrowh(pb + 7 * 80 + m8 * 8, D1);   // M3_1^T row i

      float Cv[4], Dv[4];
      Cv[0] = dot8h(A0, B0); Cv[1] = dot8h(A0, B1);
      Cv[2] = dot8h(A1, B0); Cv[3] = dot8h(A1, B1);
      Dv[0] = dot8h(C0, D0); Dv[1] = dot8h(C0, D1);
      Dv[2] = dot8h(C1, D0); Dv[3] = dot8h(C1, D1);

      const int x = xtile + px;
      float* op = obase + x * 16;
#pragma unroll
      for (int g = 0; g < 4; ++g) {
        float4 rr;
        rr.x = wred64(Cv[g] * Dv[0]);
        rr.y = wred64(Cv[g] * Dv[1]);
        rr.z = wred64(Cv[g] * Dv[2]);
        rr.w = wred64(Cv[g] * Dv[3]);
        if (lane == 63 && x < WO) *(float4*)(op + g * 4) = rr;
      }
    }
  }
}

extern "C" void kernel_launch(void* const* d_in, const int* in_sizes, int n_in,
                              void* d_out, int out_size, void* d_ws, size_t ws_size,
                              hipStream_t stream) {
  (void)in_sizes; (void)n_in; (void)d_ws; (void)ws_size; (void)out_size;
  const float* ch    = (const float*)d_in[0];  // [2,8,128,128,4] f32
  const float* cores = (const float*)d_in[1];  // [4,2,8,8,4,4]   f32
  float* out = (float*)d_out;                  // [8,127,127,16]  f32
  convsbs_fused<<<8 * 127, 256, 0, stream>>>(ch, cores, out);
}

// Round 7
// 115.735 us; speedup vs baseline: 1.3898x; 1.0355x over previous
//
#include <hip/hip_runtime.h>

// ConvSBS fused, R6: R5b's MFMA stage-1 (verified) + exec-masked C-frag
// writes (cols 8-15 are duplicates -> mask nn<8, dump region deleted),
// bank-spread px slots (PXSTR 664 halfs = 332 dw = 12 mod 32), and R4's
// verified cheap tail (4-step DPP rowsum + sbuf transpose + coalesced
// 16-lane store) instead of the 6-step full-wave reduction.

typedef __fp16 h2 __attribute__((ext_vector_type(2)));
typedef __fp16 h4 __attribute__((ext_vector_type(4)));
typedef __fp16 h8 __attribute__((ext_vector_type(8)));
typedef float  f4 __attribute__((ext_vector_type(4)));

#define NB 8
#define NH 128
#define NW 128
#define HO 127
#define WO 127
#define CH1_OFF (NB*NH*NW*4)   // 524288 floats
#define PXSTR 664              // halfs per pixel slot (640 used)
#define SSTR  20               // sbuf row stride in floats

#define PIN() asm volatile("" ::: "memory")

#define DPP_ADD(v, ctrl) \
  ((v) + __int_as_float(__builtin_amdgcn_update_dpp( \
      0, __float_as_int(v), (ctrl), 0xf, 0xf, true)))

// sum over each 16-lane row; result valid in lanes 15 mod 16 (R4-verified)
__device__ __forceinline__ float rowsum16(float v) {
  v = DPP_ADD(v, 0x111);
  v = DPP_ADD(v, 0x112);
  v = DPP_ADD(v, 0x114);
  v = DPP_ADD(v, 0x118);
  return v;
}

#define FDOT2(a, b, c) __builtin_amdgcn_fdot2((a), (b), (c), false)
#define PKRTZ(a, b)    __builtin_amdgcn_cvt_pkrtz((a), (b))

__device__ __forceinline__ float dot8h(const h2* a, const h2* b) {
  float s = FDOT2(a[0], b[0], 0.f);
  s = FDOT2(a[1], b[1], s);
  s = FDOT2(a[2], b[2], s);
  s = FDOT2(a[3], b[3], s);
  return s;
}

__device__ __forceinline__ void ldrowh(const __fp16* p, h2* d) {
  h8 v = *(const h8*)p;
  d[0] = (h2){v[0], v[1]};
  d[1] = (h2){v[2], v[3]};
  d[2] = (h2){v[4], v[5]};
  d[3] = (h2){v[6], v[7]};
}

__global__ __launch_bounds__(256, 3)
void convsbs_fused(const float* __restrict__ ch,
                   const float* __restrict__ cores,
                   float* __restrict__ out) {
  const int tid  = threadIdx.x;
  const int lane = tid & 63;
  const int wid  = tid >> 6;
  const int quad = lane >> 4;   // MFMA k-group / C-row group
  const int nn   = lane & 15;   // MFMA m (A) / n (B,D) index
  const int m8   = lane >> 3;   // s2: i
  const int x8   = lane & 7;    // s2: k
  const int rrow = lane >> 4;   // 16-lane row id
  const int o16  = lane & 15;   // output component for final gather

  __shared__ __align__(16) __fp16 tlds[4][8 * PXSTR];
  __shared__ __align__(16) float  slds[4][4 * SSTR];
  __fp16* tbuf = tlds[wid];
  float*  sbuf = slds[wid];

  // stage-1 write base (meaningful only for nn<8; writes are exec-masked)
  __fp16* wrbase = tbuf + nn * PXSTR + quad * 4;
  const bool wr = (nn < 8);

  // ---- W as 32 A-fragments: lane holds A[m=nn][k=quad*4+j], j=0..3.
  // cores layout [c][q][l][r][a*4+b]; k = quad*4+j -> a=quad, b=j (float4).
  // cores 0,2: rows ordered (q,l,r); cores 1,3: (q,r,l) -> transposed store,
  // matching stage 2's M1^T / M3^T row reads.  (R5b-verified)
  h4 wf[4][8];
#pragma unroll
  for (int c = 0; c < 4; ++c)
#pragma unroll
    for (int bi = 0; bi < 8; ++bi) {
      const int rowIdx = bi * 16 + nn;       // 0..127 within core c
      const int q  = rowIdx >> 6;
      const int ua = (rowIdx >> 3) & 7;
      const int ub = rowIdx & 7;
      const int l = (c & 1) ? ub : ua;
      const int r = (c & 1) ? ua : ub;
      const float4 wv = *(const float4*)(
          cores + ((((c * 2 + q) * 8 + l) * 8 + r) << 4) + quad * 4);
      h2 p0 = PKRTZ(wv.x, wv.y), p1 = PKRTZ(wv.z, wv.w);
      wf[c][bi] = (h4){p0[0], p0[1], p1[0], p1[1]};
    }

  const int blk = blockIdx.x;       // one (b, y) row per block
  const int b = blk / 127;
  const int y = blk - b * 127;
  const int xq = wid * 32;          // wave's x-quarter: 4 tiles of 8
  const float* rowbase = ch + (size_t)((b * NH + y) * NW) * 4;
  float* obase = out + (size_t)((b * HO + y) * WO) * 16;

  float  a0[2][4];
  float4 a1[2][4];
  auto loadch = [&](int xtile, int bufi) {
#pragma unroll
    for (int c = 0; c < 4; ++c) {
      int col = xtile + x8 + (c & 1);
      col = col > 127 ? 127 : col;            // clamp (x=127 output is masked)
      const float* cp = rowbase + (((c >> 1) * NW) + col) * 4;
      a0[bufi][c] = cp[quad];                  // ch0[a=quad]
      a1[bufi][c] = *(const float4*)(cp + CH1_OFF);  // ch1[0..3]
    }
  };

  loadch(xq, 0);

#pragma unroll
  for (int t = 0; t < 4; ++t) {
    const int xtile = xq + t * 8;
    const int cb = t & 1;

    // B-fragments: B[k=ab][n=px] = ch0[a]*ch1[b] at core-shifted position
    h4 bf[4];
#pragma unroll
    for (int c = 0; c < 4; ++c) {
      const float s = a0[cb][c];
      const float4 v = a1[cb][c];
      h2 p0 = PKRTZ(s * v.x, s * v.y), p1 = PKRTZ(s * v.z, s * v.w);
      bf[c] = (h4){p0[0], p0[1], p1[0], p1[1]};
    }
    if (t < 3) loadch(xq + (t + 1) * 8, cb ^ 1);

    // ---- stage 1: 32 MFMAs; each C-frag -> one exec-masked ds_write_b64.
    // addr(rowIdx=bi*16+quad*4+reg) = c*160 + rowIdx + (rowIdx>=64 ? 16 : 0)
#pragma unroll
    for (int c = 0; c < 4; ++c)
#pragma unroll
      for (int bi = 0; bi < 8; ++bi) {
        f4 acc = __builtin_amdgcn_mfma_f32_16x16x16f16(
            wf[c][bi], bf[c], (f4){0.f, 0.f, 0.f, 0.f}, 0, 0, 0);
        h2 p0 = PKRTZ(acc[0], acc[1]), p1 = PKRTZ(acc[2], acc[3]);
        if (wr)
          *(h4*)(wrbase + c * 160 + bi * 16 + (bi >= 4 ? 16 : 0)) =
              (h4){p0[0], p0[1], p1[0], p1[1]};
      }
    PIN();

    // ---- stage 2 (R4-verified reads/dots) + R4-verified cheap tail
#pragma unroll 1
    for (int px = 0; px < 8; ++px) {
      const __fp16* pb = tbuf + px * PXSTR;
      h2 A0[4], A1[4], B0[4], B1[4], C0[4], C1[4], D0[4], D1[4];
      ldrowh(pb + 0 * 80 + m8 * 8, A0);   // M0_0 row i
      ldrowh(pb + 1 * 80 + m8 * 8, A1);   // M0_1 row i
      ldrowh(pb + 2 * 80 + x8 * 8, B0);   // M1_0^T row k
      ldrowh(pb + 3 * 80 + x8 * 8, B1);   // M1_1^T row k
      ldrowh(pb + 4 * 80 + x8 * 8, C0);   // M2_0 row k
      ldrowh(pb + 5 * 80 + x8 * 8, C1);   // M2_1 row k
      ldrowh(pb + 6 * 80 + m8 * 8, D0);   // M3_0^T row i
      ldrowh(pb + 7 * 80 + m8 * 8, D1);   // M3_1^T row i

      float Cv[4], Dv[4];
      Cv[0] = dot8h(A0, B0); Cv[1] = dot8h(A0, B1);
      Cv[2] = dot8h(A1, B0); Cv[3] = dot8h(A1, B1);
      Dv[0] = dot8h(C0, D0); Dv[1] = dot8h(C0, D1);
      Dv[2] = dot8h(C1, D0); Dv[3] = dot8h(C1, D1);

      // 4-step DPP rowsum; lanes 15 mod 16 write float4 chunks to sbuf
#pragma unroll
      for (int pq = 0; pq < 4; ++pq) {
        float4 rr;
        rr.x = rowsum16(Cv[pq] * Dv[0]);
        rr.y = rowsum16(Cv[pq] * Dv[1]);
        rr.z = rowsum16(Cv[pq] * Dv[2]);
        rr.w = rowsum16(Cv[pq] * Dv[3]);
        if ((lane & 15) == 15)
          *(float4*)(sbuf + rrow * SSTR + pq * 4) = rr;
      }
      PIN();

      // gather the 4 row-group partials; coalesced 16-lane store
      float v = sbuf[0 * SSTR + o16] + sbuf[1 * SSTR + o16]
              + sbuf[2 * SSTR + o16] + sbuf[3 * SSTR + o16];
      const int x = xtile + px;
      if (lane < 16 && x < WO) obase[x * 16 + o16] = v;
      PIN();
    }
  }
}

extern "C" void kernel_launch(void* const* d_in, const int* in_sizes, int n_in,
                              void* d_out, int out_size, void* d_ws, size_t ws_size,
                              hipStream_t stream) {
  (void)in_sizes; (void)n_in; (void)d_ws; (void)ws_size; (void)out_size;
  const float* ch    = (const float*)d_in[0];  // [2,8,128,128,4] f32
  const float* cores = (const float*)d_in[1];  // [4,2,8,8,4,4]   f32
  float* out = (float*)d_out;                  // [8,127,127,16]  f32
  convsbs_fused<<<8 * 127, 256, 0, stream>>>(ch, cores, out);
}

// Round 9
// 87.430 us; speedup vs baseline: 1.8397x; 1.3237x over previous
//
#include <hip/hip_runtime.h>

// ConvSBS fused, R7b: ALL-MFMA pipeline (compile-fixed R7).
//  stage A (R6-verified): t[qlr, px] = W(512x16).P(16x8) -> LDS px slots
//  stage B: per px, two 16x16x16 MFMAs:
//    Ct[(q,kb),(p,i)] = sum_j M1q[j,kb]*M0p[i,j]   (A=t1T rows, B=t0 rows)
//    D [(r,kb),(s,i)] = sum_l M2r[kb,l]*M3s[l,i]   (A=t2 rows, B=t3T rows)
//    C-layout regs (4 rows, contiguous kb) pack -> one ds_write_b64 each,
//    landing as C'[pq][i*8+kb], D'[rs][i*8+kb] (f16).
//  stage E: 4 pixels per MFMA chain via block-diagonal batching:
//    A[m=(px,pq)][k2] = C'_px[pq][k2], B[k2][n=(px,rs)] = D'_px[rs][k2];
//    diagonal px blocks = out[pq,rs]; 4 chained 16x16x16 (K=64).
//    E C-layout: px on quad -> sbuf transpose -> ONE coalesced 256B store/4px.

typedef __fp16 h2 __attribute__((ext_vector_type(2)));
typedef __fp16 h4 __attribute__((ext_vector_type(4)));
typedef float  f4 __attribute__((ext_vector_type(4)));

#define NB 8
#define NH 128
#define NW 128
#define HO 127
#define WO 127
#define CH1_OFF (NB*NH*NW*4)   // 524288 floats
#define PXSTR 664              // halfs per px slot (640 used; R6-verified)
#define ZOFF  648              // zeroed 8B pad inside each slot (K=8 pad reads)
#define CDROW 68               // C'/D' row stride (halfs): 136B, 8B-aligned
#define CDSTR 552              // per-px C'/D' stride (halfs): 8*68=544 used
#define SS    20               // sbuf row stride (floats)

#define PIN() asm volatile("" ::: "memory")
#define PKRTZ(a, b) __builtin_amdgcn_cvt_pkrtz((a), (b))

__device__ __forceinline__ f4 mfma16(h4 a, h4 b, f4 c) {
  return __builtin_amdgcn_mfma_f32_16x16x16f16(a, b, c, 0, 0, 0);
}

__global__ __launch_bounds__(256, 2)
void convsbs_fused(const float* __restrict__ ch,
                   const float* __restrict__ cores,
                   float* __restrict__ out) {
  const int tid  = threadIdx.x;
  const int lane = tid & 63;
  const int wid  = tid >> 6;
  const int quad = lane >> 4;   // MFMA k-group / C-row group
  const int nn   = lane & 15;   // MFMA m/n index
  const int x8   = lane & 7;
  const f4 F4Z = {0.f, 0.f, 0.f, 0.f};

  __shared__ __align__(16) __fp16 tlds[4][8 * PXSTR];
  __shared__ __align__(16) __fp16 cdlds[4][4 * CDSTR];
  __shared__ __align__(16) float  slds[4][4 * SS];
  __fp16* tbuf = tlds[wid];
  __fp16* cdb  = cdlds[wid];
  float*  sbuf = slds[wid];

  // zero the K=8 pad target in each px slot (read by quads 2,3 in stage B)
  if (lane < 8) *(h4*)(tbuf + lane * PXSTR + ZOFF) = (h4){0, 0, 0, 0};
  PIN();

  // stage-A write base (nn<8; cols 8-15 duplicate)  [R6-verified]
  __fp16* wrbase = tbuf + nn * PXSTR + quad * 4;
  const bool wr = (nn < 8);

  // ---- W as 32 A-fragments (R5b/R6-verified)
  h4 wf[4][8];
#pragma unroll
  for (int c = 0; c < 4; ++c)
#pragma unroll
    for (int bi = 0; bi < 8; ++bi) {
      const int rowIdx = bi * 16 + nn;
      const int q  = rowIdx >> 6;
      const int ua = (rowIdx >> 3) & 7;
      const int ub = rowIdx & 7;
      const int l = (c & 1) ? ub : ua;
      const int r = (c & 1) ? ua : ub;
      const float4 wv = *(const float4*)(
          cores + ((((c * 2 + q) * 8 + l) * 8 + r) << 4) + quad * 4);
      h2 p0 = PKRTZ(wv.x, wv.y), p1 = PKRTZ(wv.z, wv.w);
      wf[c][bi] = (h4){p0[0], p0[1], p1[0], p1[1]};
    }

  // ---- hoisted, lane-constant stage-B/E LDS offsets (halfs)
  const int hq = nn >> 3, hb = nn & 7;
  // Ct: A[(q,kb)][j] = t1T[q][kb][j]   B[j][(p,i)] = t0[p][i][j]
  const int ctA = (quad < 2) ? ((2 + hq) * 80 + hb * 8 + quad * 4) : ZOFF;
  const int ctB = (quad < 2) ? ( hq      * 80 + hb * 8 + quad * 4) : ZOFF;
  // D:  A[(r,kb)][l] = t2[r][kb][l]    B[l][(s,i)] = t3T[s][i][l]
  const int dA  = (quad < 2) ? ((4 + hq) * 80 + hb * 8 + quad * 4) : ZOFF;
  const int dB  = (quad < 2) ? ((6 + hq) * 80 + hb * 8 + quad * 4) : ZOFF;
  // C-layout -> C'[pq][i*8+kb] / D'[rs][i*8+kb] writes (contiguous kb)
  const int ctW = (hq * 2 + (quad >> 1)) * CDROW + hb * 8 + (quad & 1) * 4;
  const int dW  = (4 + (quad >> 1) * 2 + hq) * CDROW + hb * 8 + (quad & 1) * 4;
  // E: A lane nn=(px,pq): C'_px row pq; B lane nn=(px,rs): D'_px row rs
  const int eA  = (nn >> 2) * CDSTR + (nn & 3) * CDROW + quad * 4;
  const int eB  = (nn >> 2) * CDSTR + (4 + (nn & 3)) * CDROW + quad * 4;
  // sbuf transpose: lanes with nn>>2==quad hold px=quad, rs=nn&3, pq=reg
  const bool sW = ((nn >> 2) == quad);
  const int sWo = quad * SS + (nn & 3) * 4;
  const int sRo = quad * SS + (nn & 3) * 4 + (nn >> 2);  // read [px][rs*4+pq]

  const int blk = blockIdx.x;       // one (b,y) row per block
  const int b = blk / 127;
  const int y = blk - b * 127;
  const int xq = wid * 32;          // wave's x-quarter
  const float* rowbase = ch + (size_t)((b * NH + y) * NW) * 4;
  float* obase = out + (size_t)((b * HO + y) * WO) * 16;

  float  a0[2][4];
  float4 a1[2][4];
  auto loadch = [&](int xtile, int bufi) {
#pragma unroll
    for (int c = 0; c < 4; ++c) {
      int col = xtile + x8 + (c & 1);
      col = col > 127 ? 127 : col;
      const float* cp = rowbase + (((c >> 1) * NW) + col) * 4;
      a0[bufi][c] = cp[quad];
      a1[bufi][c] = *(const float4*)(cp + CH1_OFF);
    }
  };

  loadch(xq, 0);

#pragma unroll
  for (int t = 0; t < 4; ++t) {
    const int cb = t & 1;

    // ---- stage A (R6-verified): B-frags + 32 MFMA + masked b64 writes
    h4 bf[4];
#pragma unroll
    for (int c = 0; c < 4; ++c) {
      const float s = a0[cb][c];
      const float4 v = a1[cb][c];
      h2 p0 = PKRTZ(s * v.x, s * v.y), p1 = PKRTZ(s * v.z, s * v.w);
      bf[c] = (h4){p0[0], p0[1], p1[0], p1[1]};
    }
    if (t < 3) loadch(xq + (t + 1) * 8, cb ^ 1);

#pragma unroll
    for (int c = 0; c < 4; ++c)
#pragma unroll
      for (int bi = 0; bi < 8; ++bi) {
        f4 acc = mfma16(wf[c][bi], bf[c], F4Z);
        h2 p0 = PKRTZ(acc[0], acc[1]), p1 = PKRTZ(acc[2], acc[3]);
        if (wr)
          *(h4*)(wrbase + c * 160 + bi * 16 + (bi >= 4 ? 16 : 0)) =
              (h4){p0[0], p0[1], p1[0], p1[1]};
      }
    PIN();

    // ---- stage B + E, two 4-px groups
#pragma unroll
    for (int g = 0; g < 2; ++g) {
#pragma unroll
      for (int p4 = 0; p4 < 4; ++p4) {
        const __fp16* slot = tbuf + (g * 4 + p4) * PXSTR;
        __fp16* cd = cdb + p4 * CDSTR;
        // Ct = M1T . M0T  (16x16, K=8 zero-padded)
        h4 a1f = *(const h4*)(slot + ctA);
        h4 b1f = *(const h4*)(slot + ctB);
        f4 c0 = mfma16(a1f, b1f, F4Z);
        h2 u0 = PKRTZ(c0[0], c0[1]), u1 = PKRTZ(c0[2], c0[3]);
        *(h4*)(cd + ctW) = (h4){u0[0], u0[1], u1[0], u1[1]};
        // D = M2 . M3T
        h4 a2f = *(const h4*)(slot + dA);
        h4 b2f = *(const h4*)(slot + dB);
        f4 d0 = mfma16(a2f, b2f, F4Z);
        h2 v0 = PKRTZ(d0[0], d0[1]), v1 = PKRTZ(d0[2], d0[3]);
        *(h4*)(cd + dW) = (h4){v0[0], v0[1], v1[0], v1[1]};
      }
      PIN();

      // ---- E: 4 px per MFMA chain (K=64, diagonal px blocks)
      f4 e = F4Z;
#pragma unroll
      for (int kb = 0; kb < 4; ++kb) {
        h4 ea = *(const h4*)(cdb + eA + kb * 16);
        h4 eb = *(const h4*)(cdb + eB + kb * 16);
        e = mfma16(ea, eb, e);
      }
      // useful lanes: col px == row px (quad); write [px][rs*4 + pq(=reg)]
      if (sW) *(float4*)(sbuf + sWo) = make_float4(e[0], e[1], e[2], e[3]);
      PIN();

      // coalesced 256B store: lane (quad=px, nn=o16)
      const float v = sbuf[sRo];
      const int x4 = xq + t * 8 + g * 4 + quad;
      if (x4 < WO) obase[x4 * 16 + nn] = v;
      PIN();
    }
  }
}

extern "C" void kernel_launch(void* const* d_in, const int* in_sizes, int n_in,
                              void* d_out, int out_size, void* d_ws, size_t ws_size,
                              hipStream_t stream) {
  (void)in_sizes; (void)n_in; (void)d_ws; (void)ws_size; (void)out_size;
  const float* ch    = (const float*)d_in[0];  // [2,8,128,128,4] f32
  const float* cores = (const float*)d_in[1];  // [4,2,8,8,4,4]   f32
  float* out = (float*)d_out;                  // [8,127,127,16]  f32
  convsbs_fused<<<8 * 127, 256, 0, stream>>>(ch, cores, out);
}